// Round 6
// baseline (764.838 us; speedup 1.0000x reference)
//
#include <hip/hip_runtime.h>
#include <math.h>

// Problem constants (B=4, S=512, H=2048, E=16, K=4)
#define M_TOK 2048
#define H_    2048
#define H2_   1024
#define E_    16
#define CAP_  768
#define ALPHA_ 0.7f
#define WSCALE 64.0f
#define INV_WSCALE (1.0f / 64.0f)

typedef _Float16 half8 __attribute__((ext_vector_type(8)));
typedef float f32x4 __attribute__((ext_vector_type(4)));

typedef __attribute__((address_space(1))) const unsigned int* gas_ptr;
typedef __attribute__((address_space(3))) unsigned int* las_ptr;

__device__ __forceinline__ void load_lds16(const void* g, void* l) {
    __builtin_amdgcn_global_load_lds((gas_ptr)g, (las_ptr)l, 16, 0, 0);
}

// split 8 fp32 -> half8 hi + half8 lo
__device__ __forceinline__ void split8(const f32x4 a, const f32x4 b,
                                       half8* hi, half8* lo) {
#pragma unroll
    for (int i = 0; i < 4; ++i) {
        _Float16 h0 = (_Float16)a[i];
        (*hi)[i] = h0;
        (*lo)[i] = (_Float16)(a[i] - (float)h0);
        _Float16 h1 = (_Float16)b[i];
        (*hi)[i + 4] = h1;
        (*lo)[i + 4] = (_Float16)(b[i] - (float)h1);
    }
}

// A2 layout for activations: [K/32][M_TOK][32] f16 (plane stride = M_TOK*32 = 65536).
// Each K-step slice of 16 rows is a contiguous 1KB block -> coalesced per-lane
// global->register fragment loads, no LDS round-trip for the A operand.

// ---------------------------------------------------------------------------
// Activation split: fp32 [M,2048] -> f16 hi/lo in A2 layout
// (also used for Wm2, which is [2048,2048] row-major = same geometry)
// ---------------------------------------------------------------------------
struct ADesc { const float* A; _Float16* oh; _Float16* ol; };
struct APack { ADesc g[4]; };

__global__ __launch_bounds__(256) void asplit_kernel(APack pack)
{
    ADesc d;
    switch (blockIdx.z) {
        case 0: d = pack.g[0]; break;
        case 1: d = pack.g[1]; break;
        case 2: d = pack.g[2]; break;
        default: d = pack.g[3]; break;
    }
    const size_t i = ((size_t)blockIdx.x * 256 + threadIdx.x) * 8;
    f32x4 v0 = *(const f32x4*)(d.A + i);
    f32x4 v1 = *(const f32x4*)(d.A + i + 4);
    half8 h, l;
    split8(v0, v1, &h, &l);
    const size_t row = i >> 11;          // K = 2048
    const size_t c0  = i & 2047;
    const size_t o2  = ((c0 >> 5) << 16) + row * 32 + (c0 & 31);
    *(half8*)(d.oh + o2) = h;
    *(half8*)(d.ol + o2) = l;
}

// ---------------------------------------------------------------------------
// Weight split+transpose: W fp32 [K,N] -> Wt_h/Wt_l f16 [N,K], scaled.
// scale=64 for raw weights; scale=1 for the (already x64) W23 partials.
// ---------------------------------------------------------------------------
struct WDesc { const float* W; _Float16* oh; _Float16* ol; int K; int N; float scale; };
struct WPack { WDesc g[6]; };

__global__ __launch_bounds__(256) void wsplit_kernel(WPack pack)
{
    WDesc d;
    switch (blockIdx.z) {
        case 0: d = pack.g[0]; break;
        case 1: d = pack.g[1]; break;
        case 2: d = pack.g[2]; break;
        case 3: d = pack.g[3]; break;
        case 4: d = pack.g[4]; break;
        default: d = pack.g[5]; break;
    }
    const int n0 = blockIdx.y * 64;
    if (n0 >= d.N) return;
    const int k0 = blockIdx.x * 64;

    __shared__ float T[64][68];
    const int t = threadIdx.x;

    {
        const int kr = t >> 2;
        const int c0 = (t & 3) << 4;
        const float* src = d.W + (size_t)(k0 + kr) * d.N + n0 + c0;
        f32x4 v0 = *(const f32x4*)(src);
        f32x4 v1 = *(const f32x4*)(src + 4);
        f32x4 v2 = *(const f32x4*)(src + 8);
        f32x4 v3 = *(const f32x4*)(src + 12);
#pragma unroll
        for (int i = 0; i < 4; ++i) T[c0 + i][kr]      = v0[i];
#pragma unroll
        for (int i = 0; i < 4; ++i) T[c0 + 4 + i][kr]  = v1[i];
#pragma unroll
        for (int i = 0; i < 4; ++i) T[c0 + 8 + i][kr]  = v2[i];
#pragma unroll
        for (int i = 0; i < 4; ++i) T[c0 + 12 + i][kr] = v3[i];
    }
    __syncthreads();

    {
        const int n  = t >> 2;
        const int kj = (t & 3) << 4;
        half8 h0, l0, h1, l1;
        f32x4 u0 = *(const f32x4*)&T[n][kj];
        f32x4 u1 = *(const f32x4*)&T[n][kj + 4];
        f32x4 u2 = *(const f32x4*)&T[n][kj + 8];
        f32x4 u3 = *(const f32x4*)&T[n][kj + 12];
        const float sc = d.scale;
        u0 *= sc; u1 *= sc; u2 *= sc; u3 *= sc;
        split8(u0, u1, &h0, &l0);
        split8(u2, u3, &h1, &l1);
        const size_t o = (size_t)(n0 + n) * d.K + k0 + kj;
        *(half8*)(d.oh + o)     = h0;
        *(half8*)(d.oh + o + 8) = h1;
        *(half8*)(d.ol + o)     = l0;
        *(half8*)(d.ol + o + 8) = l1;
    }
}

// ---------------------------------------------------------------------------
// b23[m][n] = bm2 @ Ws1[2+m][:,n] + bs1[2+m][n]   (m=0,1; n<1024)  fp32
// ---------------------------------------------------------------------------
__global__ __launch_bounds__(256) void b23_kernel(
    const float* __restrict__ bm2, const float* __restrict__ Ws1,
    const float* __restrict__ bs1, float* __restrict__ b23)
{
    const int idx = blockIdx.x * 256 + threadIdx.x;   // 0..2047
    const int m = idx >> 10;
    const int n = idx & 1023;
    const float* W = Ws1 + (size_t)(2 + m) * H_ * H2_ + n;
    float s = 0.f;
    for (int k = 0; k < H_; ++k) s = fmaf(bm2[k], W[(size_t)k * H2_], s);
    b23[idx] = s + bs1[(2 + m) * H2_ + n];
}

// ---------------------------------------------------------------------------
// f16x3 MFMA GEMM, 256x256 tile (R5 schedule, unchanged K-loop):
//   512 threads = 8 waves (4M x 2N); per-wave 64x128 = acc[4][8].
//   A: A2 layout, global->reg each K-step. B: [N,K] h/l via global_load_lds,
//   double-buffered 64 KB LDS; vmcnt(4) counted wait.
// mode 0: fp32 out (+bias,+relu); mode 1: f16 hi/lo out in A2 layout;
// mode 2: raw fp32 partial (no bias/scale).
// ---------------------------------------------------------------------------
struct GDesc {
    const _Float16* Ah; const _Float16* Al;
    const _Float16* Wh; const _Float16* Wl;
    const float* bias; float* Cf; _Float16* Ch; _Float16* Cl;
    int K; int ldk; int k0; int N; int ntn; int relu; int mode;
};
struct GPack { GDesc g[8]; };

__global__ __launch_bounds__(512, 2) void gemm_mfma_kernel(GPack pack)
{
    GDesc d;
    switch (blockIdx.z) {
        case 0: d = pack.g[0]; break;
        case 1: d = pack.g[1]; break;
        case 2: d = pack.g[2]; break;
        case 3: d = pack.g[3]; break;
        case 4: d = pack.g[4]; break;
        case 5: d = pack.g[5]; break;
        case 6: d = pack.g[6]; break;
        default: d = pack.g[7]; break;
    }
    const int mt_ = blockIdx.x >> 2;
    const int nt_ = (blockIdx.y << 2) + (blockIdx.x & 3);
    if (nt_ >= d.ntn) return;
    const int bm = mt_ * 256, bn = nt_ * 256;
    const int K = d.K, N = d.N, ldk = d.ldk;

    // B granule layout (<=2-way bank aliasing, verified conflict-free)
    __shared__ _Float16 Bh_s[2][256 * 32];   // 16 KB x 2
    __shared__ _Float16 Bl_s[2][256 * 32];   // total 64 KB

    const int tid  = threadIdx.x;
    const int lane = tid & 63;
    const int wave = tid >> 6;               // 0..7
    const int wm = wave >> 1, wn = wave & 1; // 4M x 2N

    size_t b_goff[2];
    int    s_lo[2];
#pragma unroll
    for (int is = 0; is < 2; ++is) {
        const int g = tid + (is << 9);
        const int row = g >> 2;
        const int q = ((g & 3) - (row >> 1)) & 3;
        b_goff[is] = (size_t)(bn + row) * ldk + d.k0 + q * 8;
        s_lo[is]   = g * 8;
    }

    const int bn0  = wn * 128 + (lane & 15);
    const int boff = (bn0 * 4 + (((lane >> 4) + (bn0 >> 1)) & 3)) * 8;

    const int aoff0 = (bm + wm * 64 + (lane & 15)) * 32 + (lane >> 4) * 8;
    const int aplane0 = d.k0 >> 5;

    f32x4 acc[4][8];
#pragma unroll
    for (int i = 0; i < 4; ++i)
#pragma unroll
        for (int j = 0; j < 8; ++j) acc[i][j] = (f32x4)0.f;

    auto issue_tile = [&](int kk, int c) {
#pragma unroll
        for (int is = 0; is < 2; ++is) {
            load_lds16(d.Wh + b_goff[is] + kk, &Bh_s[c][s_lo[is]]);
            load_lds16(d.Wl + b_goff[is] + kk, &Bl_s[c][s_lo[is]]);
        }
    };

    issue_tile(0, 0);

    const int niter = K >> 5;
    for (int it = 0; it < niter; ++it) {
        const int cur = it & 1;

        half8 fAh[4], fAl[4];
        {
            const size_t pl = ((size_t)(aplane0 + it)) << 16;
            const _Float16* pah = d.Ah + pl + aoff0;
            const _Float16* pal = d.Al + pl + aoff0;
#pragma unroll
            for (int mt = 0; mt < 4; ++mt) {
                fAh[mt] = *(const half8*)(pah + mt * 512);
                fAl[mt] = *(const half8*)(pal + mt * 512);
            }
        }

        asm volatile("" ::: "memory");
        __builtin_amdgcn_s_barrier();

        if (it + 1 < niter) {
            issue_tile((it + 1) << 5, cur ^ 1);
            asm volatile("s_waitcnt vmcnt(4)" ::: "memory");
        } else {
            asm volatile("s_waitcnt vmcnt(0)" ::: "memory");
        }

        __builtin_amdgcn_s_barrier();
        asm volatile("" ::: "memory");

        __builtin_amdgcn_s_setprio(1);
#pragma unroll
        for (int nt = 0; nt < 8; ++nt) {
            half8 fBh = *(const half8*)&Bh_s[cur][boff + nt * 512];
            half8 fBl = *(const half8*)&Bl_s[cur][boff + nt * 512];
#pragma unroll
            for (int mt = 0; mt < 4; ++mt) {
                acc[mt][nt] = __builtin_amdgcn_mfma_f32_16x16x32_f16(
                    fAh[mt], fBh, acc[mt][nt], 0, 0, 0);
                acc[mt][nt] = __builtin_amdgcn_mfma_f32_16x16x32_f16(
                    fAh[mt], fBl, acc[mt][nt], 0, 0, 0);
                acc[mt][nt] = __builtin_amdgcn_mfma_f32_16x16x32_f16(
                    fAl[mt], fBh, acc[mt][nt], 0, 0, 0);
            }
        }
        __builtin_amdgcn_s_setprio(0);
    }

    // epilogue: C/D layout col=lane&15, row=(lane>>4)*4+reg
    const int erow0 = bm + wm * 64 + ((lane >> 4) << 2);
    const int ecol0 = bn + wn * 128 + (lane & 15);
#pragma unroll
    for (int nt = 0; nt < 8; ++nt) {
        const int col = ecol0 + nt * 16;
        const float bb = (d.mode == 2) ? 0.f : d.bias[col];
        const size_t colbase = ((size_t)(col >> 5) << 16) + (size_t)(col & 31);
#pragma unroll
        for (int mt = 0; mt < 4; ++mt) {
            f32x4 a = acc[mt][nt];
#pragma unroll
            for (int r = 0; r < 4; ++r) {
                const int rr = erow0 + mt * 16 + r;
                if (d.mode == 2) {
                    d.Cf[(size_t)rr * N + col] = a[r];      // raw partial
                } else {
                    float v = a[r] * INV_WSCALE + bb;
                    if (d.relu) v = fmaxf(v, 0.f);
                    if (d.mode == 0) {
                        d.Cf[(size_t)rr * N + col] = v;
                    } else {
                        const size_t o2 = colbase + (size_t)rr * 32;
                        _Float16 h = (_Float16)v;
                        d.Ch[o2] = h;
                        d.Cl[o2] = (_Float16)(v - (float)h);
                    }
                }
            }
        }
    }
}

// ---------------------------------------------------------------------------
// 4-way split-K combine: Cf = (P0+P1+P2+P3)*(1/64) + bias, relu. fp32 out.
// ---------------------------------------------------------------------------
struct C4Desc {
    const float* P0; const float* P1; const float* P2; const float* P3;
    const float* bias; float* Cf; int N;
};
struct C4Pack { C4Desc g[2]; };

__global__ __launch_bounds__(256) void combine4_kernel(C4Pack pack)
{
    C4Desc d;
    switch (blockIdx.z) {
        case 0: d = pack.g[0]; break;
        default: d = pack.g[1]; break;
    }
    const size_t i = ((size_t)blockIdx.x * 256 + threadIdx.x) * 8;
    f32x4 s0 = *(const f32x4*)(d.P0 + i)     + *(const f32x4*)(d.P1 + i);
    f32x4 s1 = *(const f32x4*)(d.P0 + i + 4) + *(const f32x4*)(d.P1 + i + 4);
    s0 += *(const f32x4*)(d.P2 + i)     + *(const f32x4*)(d.P3 + i);
    s1 += *(const f32x4*)(d.P2 + i + 4) + *(const f32x4*)(d.P3 + i + 4);
    const int c0 = (int)(i & (size_t)(d.N - 1));
    f32x4 bb0 = *(const f32x4*)(d.bias + c0);
    f32x4 bb1 = *(const f32x4*)(d.bias + c0 + 4);
    f32x4 v0 = s0 * INV_WSCALE + bb0;
    f32x4 v1 = s1 * INV_WSCALE + bb1;
#pragma unroll
    for (int j = 0; j < 4; ++j) {
        v0[j] = fmaxf(v0[j], 0.f);
        v1[j] = fmaxf(v1[j], 0.f);
    }
    *(f32x4*)(d.Cf + i)     = v0;
    *(f32x4*)(d.Cf + i + 4) = v1;
}

// ---------------------------------------------------------------------------
// Batched skinny GEMM: C[M,16] = A[M,K] @ W[K,16] + bias[16]   (fp32)
// 64 rows/block (4x W-reuse vs 16-row version).
// ---------------------------------------------------------------------------
struct SDesc { const float* A; const float* W; const float* bias; float* C; int K; };
struct SPack { SDesc g[5]; };

__global__ __launch_bounds__(256) void gemm_n16_kernel(SPack pack)
{
    SDesc d;
    switch (blockIdx.z) {
        case 0: d = pack.g[0]; break;
        case 1: d = pack.g[1]; break;
        case 2: d = pack.g[2]; break;
        case 3: d = pack.g[3]; break;
        default: d = pack.g[4]; break;
    }
    __shared__ float As[64][68];
    __shared__ float Ws[64][16];

    const int tid = threadIdx.x;
    const int row0 = blockIdx.x * 64;
    const int ar = tid >> 2, ac = (tid & 3) << 4;   // A stage: row, col base
    const int wr = tid >> 2, wc = (tid & 3) << 2;   // W stage
    const int e = tid & 15, r0 = tid >> 4;          // compute: rows r0+16j

    const int K = d.K;
    float acc0 = 0.f, acc1 = 0.f, acc2 = 0.f, acc3 = 0.f;
    for (int k0 = 0; k0 < K; k0 += 64) {
        const float* asrc = &d.A[(size_t)(row0 + ar) * K + k0 + ac];
        float4 a0 = *(const float4*)(asrc);
        float4 a1 = *(const float4*)(asrc + 4);
        float4 a2 = *(const float4*)(asrc + 8);
        float4 a3 = *(const float4*)(asrc + 12);
        float4 wv = *(const float4*)&d.W[(size_t)(k0 + wr) * E_ + wc];
        if (k0) __syncthreads();
        *(float4*)&As[ar][ac]      = a0;
        *(float4*)&As[ar][ac + 4]  = a1;
        *(float4*)&As[ar][ac + 8]  = a2;
        *(float4*)&As[ar][ac + 12] = a3;
        *(float4*)&Ws[wr][wc]      = wv;
        __syncthreads();
#pragma unroll
        for (int kk = 0; kk < 64; ++kk) {
            const float w = Ws[kk][e];
            acc0 = fmaf(As[r0][kk],      w, acc0);
            acc1 = fmaf(As[r0 + 16][kk], w, acc1);
            acc2 = fmaf(As[r0 + 32][kk], w, acc2);
            acc3 = fmaf(As[r0 + 48][kk], w, acc3);
        }
    }
    const float bb = d.bias[e];
    d.C[(size_t)(row0 + r0)      * E_ + e] = acc0 + bb;
    d.C[(size_t)(row0 + r0 + 16) * E_ + e] = acc1 + bb;
    d.C[(size_t)(row0 + r0 + 32) * E_ + e] = acc2 + bb;
    d.C[(size_t)(row0 + r0 + 48) * E_ + e] = acc3 + bb;
}

// ---------------------------------------------------------------------------
// Router finalize
// ---------------------------------------------------------------------------
__device__ __forceinline__ void softmax16_acc(const float* __restrict__ lg,
                                              float w, float* __restrict__ p)
{
    float mx = lg[0];
#pragma unroll
    for (int e = 1; e < 16; ++e) mx = fmaxf(mx, lg[e]);
    float ex[16];
    float s = 0.f;
#pragma unroll
    for (int e = 0; e < 16; ++e) { ex[e] = expf(lg[e] - mx); s += ex[e]; }
    const float wi = w / s;
#pragma unroll
    for (int e = 0; e < 16; ++e) p[e] = fmaf(ex[e], wi, p[e]);
}

__global__ __launch_bounds__(256) void router_kernel(
    const float* __restrict__ GL, const float* __restrict__ SL,
    float* __restrict__ out, float* __restrict__ accum)
{
    const int t = blockIdx.x * 256 + threadIdx.x;

    float p[16];
#pragma unroll
    for (int e = 0; e < 16; ++e) p[e] = 0.f;

    softmax16_acc(GL + (size_t)t * E_, ALPHA_, p);
#pragma unroll
    for (int m = 0; m < 4; ++m)
        softmax16_acc(SL + ((size_t)m * M_TOK + t) * E_, (1.f - ALPHA_) * 0.5f, p);

    const size_t NTOT = (size_t)M_TOK * E_ * CAP_;
    float* probs_out = out + 2 * NTOT + (size_t)t * E_;
#pragma unroll
    for (int e = 0; e < 16; ++e) probs_out[e] = p[e];

    float red[16];
#pragma unroll
    for (int e = 0; e < 16; ++e) red[e] = p[e];
#pragma unroll
    for (int m = 1; m < 64; m <<= 1)
#pragma unroll
        for (int e = 0; e < 16; ++e) red[e] += __shfl_xor(red[e], m);
    const int lane = threadIdx.x & 63;
#pragma unroll
    for (int e = 0; e < 16; ++e)
        if (lane == e) atomicAdd(&accum[e], red[e]);

    float tmp[16];
#pragma unroll
    for (int e = 0; e < 16; ++e) tmp[e] = p[e];
    int   bi[4];
    float bv[4];
    float s4 = 0.f;
#pragma unroll
    for (int kk = 0; kk < 4; ++kk) {
        float best = -1.f; int besti = 0;
#pragma unroll
        for (int e = 0; e < 16; ++e)
            if (tmp[e] > best) { best = tmp[e]; besti = e; }
        bi[kk] = besti; bv[kk] = best; s4 += best;
        tmp[besti] = -1.f;
    }
    const float inv = 1.f / s4;
#pragma unroll
    for (int kk = 0; kk < 4; ++kk) {
        const size_t base = ((size_t)t * E_ + bi[kk]) * CAP_;
        out[base] = 1.0f;
        out[NTOT + base] = bv[kk] * inv;
    }
}

__global__ void aux_kernel(const float* __restrict__ accum,
                           float* __restrict__ out, unsigned long long pos)
{
    if (threadIdx.x == 0 && blockIdx.x == 0) {
        float s = 0.f;
#pragma unroll
        for (int e = 0; e < 16; ++e) {
            float m = accum[e] * (1.0f / (float)M_TOK);
            s += m * logf(m * (float)E_ + 1e-9f);
        }
        out[pos] = s;
    }
}

// ---------------------------------------------------------------------------
extern "C" void kernel_launch(void* const* d_in, const int* in_sizes, int n_in,
                              void* d_out, int out_size, void* d_ws, size_t ws_size,
                              hipStream_t stream)
{
    const float* hidden = (const float*)d_in[0];
    const float* mimg   = (const float*)d_in[1];
    const float* mgen   = (const float*)d_in[2];
    const float* Wg1 = (const float*)d_in[3];
    const float* bg1 = (const float*)d_in[4];
    const float* Wg2 = (const float*)d_in[5];
    const float* bg2 = (const float*)d_in[6];
    const float* Wm1 = (const float*)d_in[7];
    const float* bm1 = (const float*)d_in[8];
    const float* Wm2 = (const float*)d_in[9];
    const float* bm2 = (const float*)d_in[10];
    const float* Ws1 = (const float*)d_in[11];  // [4,H,H2]
    const float* bs1 = (const float*)d_in[12];  // [4,H2]
    const float* Ws2 = (const float*)d_in[13];  // [4,H2,E]
    const float* bs2 = (const float*)d_in[14];  // [4,E]

    float* out = (float*)d_out;

    // workspace layout
    char* p = (char*)d_ws;
    float* accum = (float*)p;            p += 256;
    float* b23   = (float*)p;            p += 8192;              // [2][1024] fp32
    float* G1    = (float*)p;            p += (size_t)M_TOK * H_ * 4;
    float* S1    = (float*)p;            p += (size_t)4 * M_TOK * H2_ * 4;
    float* GL    = (float*)p;            p += (size_t)M_TOK * E_ * 4;
    float* SL    = (float*)p;            p += (size_t)4 * M_TOK * E_ * 4;
    _Float16* hid_h = (_Float16*)p;      p += (size_t)M_TOK * H_ * 2;
    _Float16* hid_l = (_Float16*)p;      p += (size_t)M_TOK * H_ * 2;
    _Float16* img_h = (_Float16*)p;      p += (size_t)M_TOK * H_ * 2;
    _Float16* img_l = (_Float16*)p;      p += (size_t)M_TOK * H_ * 2;
    _Float16* gen_h = (_Float16*)p;      p += (size_t)M_TOK * H_ * 2;
    _Float16* gen_l = (_Float16*)p;      p += (size_t)M_TOK * H_ * 2;
    _Float16* T1_h  = (_Float16*)p;      p += (size_t)M_TOK * H_ * 2;
    _Float16* T1_l  = (_Float16*)p;      p += (size_t)M_TOK * H_ * 2;
    _Float16* MI_h  = (_Float16*)p;      p += (size_t)M_TOK * H_ * 2;   // holds W23raw
    _Float16* MI_l  = (_Float16*)p;      p += (size_t)M_TOK * H_ * 2;
    _Float16* wm2a_h = (_Float16*)p;     p += (size_t)H_ * H_ * 2;      // Wm2 A2-split
    _Float16* wm2a_l = (_Float16*)p;     p += (size_t)H_ * H_ * 2;
    _Float16* Wg1t_h = (_Float16*)p;     p += (size_t)H_ * H_ * 2;
    _Float16* Wg1t_l = (_Float16*)p;     p += (size_t)H_ * H_ * 2;
    _Float16* Wm1t_h = (_Float16*)p;     p += (size_t)H_ * H_ * 2;
    _Float16* Wm1t_l = (_Float16*)p;     p += (size_t)H_ * H_ * 2;
    _Float16* Ws1t_h = (_Float16*)p;     p += (size_t)4 * H2_ * H_ * 2;
    _Float16* Ws1t_l = (_Float16*)p;     p += (size_t)4 * H2_ * H_ * 2;

    // Aliases (stream-ordered reuse of dead regions):
    // W23raw[m] fp32 [2048,1024] x2 -> MI_h+MI_l span (16.8 MB)
    float* W23raw = (float*)MI_h;
    // W23t h/l [2][1024][2048] f16 -> hid_h / hid_l (dead after L1)
    _Float16* W23t_h = hid_h;
    _Float16* W23t_l = hid_l;
    // pc split-K=4 partials: 8 x [2048,1024] fp32 (dead-after-L1 regions)
    float* PC[8] = { (float*)img_h, (float*)img_l, (float*)gen_h, (float*)gen_l,
                     (float*)MI_h,  (float*)MI_l,  (float*)wm2a_h, (float*)wm2a_l };

    hipMemsetAsync(d_out, 0, (size_t)out_size * sizeof(float), stream);
    hipMemsetAsync(accum, 0, 16 * sizeof(float), stream);

    const dim3 blk(256);
    const dim3 blkg(512);

    // 1) activation split (hidden, image, genomic, Wm2) -> A2 layout
    APack ap;
    ap.g[0] = {hidden, hid_h, hid_l};
    ap.g[1] = {mimg,   img_h, img_l};
    ap.g[2] = {mgen,   gen_h, gen_l};
    ap.g[3] = {Wm2,    wm2a_h, wm2a_l};
    asplit_kernel<<<dim3((M_TOK * H_) / (256 * 8), 1, 4), blk, 0, stream>>>(ap);

    // 2) weight split+transpose (x64): Wm1, Wg1, Ws1[0..3]
    WPack wp;
    wp.g[0] = {Wm1, Wm1t_h, Wm1t_l, H_, H_, WSCALE};
    wp.g[1] = {Wg1, Wg1t_h, Wg1t_l, H_, H_, WSCALE};
    for (int m = 0; m < 4; ++m)
        wp.g[2 + m] = {Ws1 + (size_t)m * H_ * H2_,
                       Ws1t_h + (size_t)m * H2_ * H_,
                       Ws1t_l + (size_t)m * H2_ * H_, H_, H2_, WSCALE};
    wsplit_kernel<<<dim3(32, 32, 6), blk, 0, stream>>>(wp);

    // 2b) fused bias b23 = bm2@Ws1[2+m] + bs1[2+m]
    b23_kernel<<<8, blk, 0, stream>>>(bm2, Ws1, bs1, b23);

    // 3) L1: pa GEMMs + W23 weight GEMMs = 256 active blocks (1/CU exact)
    //    W23raw[m] = Wm2 @ (64*Ws1[2+m])  (mode 2, raw, = 64*W23)
    GPack pa;
    pa.g[0] = {hid_h, hid_l, Wm1t_h, Wm1t_l, bm1, nullptr, T1_h, T1_l,
               H_, H_, 0, H_, 8, 1, 1};
    pa.g[1] = {hid_h, hid_l, Wg1t_h, Wg1t_l, bg1, G1, nullptr, nullptr,
               H_, H_, 0, H_, 8, 1, 0};
    pa.g[2] = {img_h, img_l, Ws1t_h + (size_t)0 * H2_ * H_, Ws1t_l + (size_t)0 * H2_ * H_,
               bs1 + 0 * H2_, S1 + (size_t)0 * M_TOK * H2_, nullptr, nullptr,
               H_, H_, 0, H2_, 4, 1, 0};
    pa.g[3] = {gen_h, gen_l, Ws1t_h + (size_t)1 * H2_ * H_, Ws1t_l + (size_t)1 * H2_ * H_,
               bs1 + 1 * H2_, S1 + (size_t)1 * M_TOK * H2_, nullptr, nullptr,
               H_, H_, 0, H2_, 4, 1, 0};
    pa.g[4] = {wm2a_h, wm2a_l, Ws1t_h + (size_t)2 * H2_ * H_, Ws1t_l + (size_t)2 * H2_ * H_,
               nullptr, W23raw + (size_t)0 * H_ * H2_, nullptr, nullptr,
               H_, H_, 0, H2_, 4, 0, 2};
    pa.g[5] = {wm2a_h, wm2a_l, Ws1t_h + (size_t)3 * H2_ * H_, Ws1t_l + (size_t)3 * H2_ * H_,
               nullptr, W23raw + (size_t)1 * H_ * H2_, nullptr, nullptr,
               H_, H_, 0, H2_, 4, 0, 2};
    pa.g[6] = pa.g[0]; pa.g[7] = pa.g[0];
    gemm_mfma_kernel<<<dim3(32, 2, 6), blkg, 0, stream>>>(pa);

    // 3b) W23raw (x64 already) -> transpose-split h/l, scale=1
    WPack wp2;
    wp2.g[0] = {W23raw + (size_t)0 * H_ * H2_, W23t_h + (size_t)0 * H2_ * H_,
                W23t_l + (size_t)0 * H2_ * H_, H_, H2_, 1.0f};
    wp2.g[1] = {W23raw + (size_t)1 * H_ * H2_, W23t_h + (size_t)1 * H2_ * H_,
                W23t_l + (size_t)1 * H2_ * H_, H_, H2_, 1.0f};
    wp2.g[2] = wp2.g[0]; wp2.g[3] = wp2.g[0]; wp2.g[4] = wp2.g[0]; wp2.g[5] = wp2.g[0];
    wsplit_kernel<<<dim3(32, 16, 2), blk, 0, stream>>>(wp2);

    // 4) pc: S1[2+m]-pre = T1 @ W23t, split-K=4 -> 256 blocks (1/CU exact)
    GPack pc;
    for (int m = 0; m < 2; ++m)
        for (int c = 0; c < 4; ++c)
            pc.g[m * 4 + c] = {T1_h, T1_l,
                W23t_h + (size_t)m * H2_ * H_, W23t_l + (size_t)m * H2_ * H_,
                nullptr, PC[m * 4 + c], nullptr, nullptr,
                H_ / 4, H_, c * (H_ / 4), H2_, 4, 0, 2};
    gemm_mfma_kernel<<<dim3(32, 1, 8), blkg, 0, stream>>>(pc);

    // 4b) combine 4-way -> S1[2], S1[3] fp32 (+b23 bias +relu)
    C4Pack cc;
    cc.g[0] = {PC[0], PC[1], PC[2], PC[3], b23,        S1 + (size_t)2 * M_TOK * H2_, H2_};
    cc.g[1] = {PC[4], PC[5], PC[6], PC[7], b23 + 1024, S1 + (size_t)3 * M_TOK * H2_, H2_};
    combine4_kernel<<<dim3((M_TOK * H2_) / (256 * 8), 1, 2), blk, 0, stream>>>(cc);

    // 5) logit GEMMs (fp32)
    SPack sp;
    sp.g[0] = {G1, Wg2, bg2, GL, H_};
    for (int m = 0; m < 4; ++m)
        sp.g[1 + m] = {S1 + (size_t)m * M_TOK * H2_, Ws2 + (size_t)m * H2_ * E_,
                       bs2 + (size_t)m * E_, SL + (size_t)m * M_TOK * E_, H2_};
    gemm_n16_kernel<<<dim3(M_TOK / 64, 1, 5), blk, 0, stream>>>(sp);

    // 6) finalize
    router_kernel<<<M_TOK / 256, blk, 0, stream>>>(GL, SL, out, accum);
    aux_kernel<<<1, 64, 0, stream>>>(accum, out, (unsigned long long)out_size - 1);
}

// Round 7
// 703.509 us; speedup vs baseline: 1.0872x; 1.0872x over previous
//
#include <hip/hip_runtime.h>
#include <math.h>

// Problem constants (B=4, S=512, H=2048, E=16, K=4)
#define M_TOK 2048
#define H_    2048
#define H2_   1024
#define E_    16
#define CAP_  768
#define ALPHA_ 0.7f
#define WSCALE 64.0f
#define INV_WSCALE (1.0f / 64.0f)

typedef _Float16 half8 __attribute__((ext_vector_type(8)));
typedef _Float16 half4 __attribute__((ext_vector_type(4)));
typedef float f32x4 __attribute__((ext_vector_type(4)));

typedef __attribute__((address_space(1))) const unsigned int* gas_ptr;
typedef __attribute__((address_space(3))) unsigned int* las_ptr;

__device__ __forceinline__ void load_lds16(const void* g, void* l) {
    __builtin_amdgcn_global_load_lds((gas_ptr)g, (las_ptr)l, 16, 0, 0);
}

// split 8 fp32 -> half8 hi + half8 lo
__device__ __forceinline__ void split8(const f32x4 a, const f32x4 b,
                                       half8* hi, half8* lo) {
#pragma unroll
    for (int i = 0; i < 4; ++i) {
        _Float16 h0 = (_Float16)a[i];
        (*hi)[i] = h0;
        (*lo)[i] = (_Float16)(a[i] - (float)h0);
        _Float16 h1 = (_Float16)b[i];
        (*hi)[i + 4] = h1;
        (*lo)[i + 4] = (_Float16)(b[i] - (float)h1);
    }
}

// A2 layout: [K/32][M_TOK][32] f16, plane stride = M_TOK*32 = 65536 elems.
// Works for any column count N: plane index = col>>5, in-plane = row*32+(col&31).

// ---------------------------------------------------------------------------
// Activation split: fp32 [2048,2048] -> f16 hi/lo in A2 layout
// (hidden, image, genomic activations + Wm2 weight: same geometry)
// ---------------------------------------------------------------------------
struct ADesc { const float* A; _Float16* oh; _Float16* ol; };
struct APack { ADesc g[4]; };

__global__ __launch_bounds__(256) void asplit_kernel(APack pack)
{
    ADesc d;
    switch (blockIdx.z) {
        case 0: d = pack.g[0]; break;
        case 1: d = pack.g[1]; break;
        case 2: d = pack.g[2]; break;
        default: d = pack.g[3]; break;
    }
    const size_t i = ((size_t)blockIdx.x * 256 + threadIdx.x) * 8;
    f32x4 v0 = *(const f32x4*)(d.A + i);
    f32x4 v1 = *(const f32x4*)(d.A + i + 4);
    half8 h, l;
    split8(v0, v1, &h, &l);
    const size_t row = i >> 11;          // K = 2048
    const size_t c0  = i & 2047;
    const size_t o2  = ((c0 >> 5) << 16) + row * 32 + (c0 & 31);
    *(half8*)(d.oh + o2) = h;
    *(half8*)(d.ol + o2) = l;
}

// ---------------------------------------------------------------------------
// Weight split+transpose: W fp32 [K,N] -> Wt_h/Wt_l f16 [N,K], scaled by 64.
// ---------------------------------------------------------------------------
struct WDesc { const float* W; _Float16* oh; _Float16* ol; int K; int N; };
struct WPack { WDesc g[6]; };

__global__ __launch_bounds__(256) void wsplit_kernel(WPack pack)
{
    WDesc d;
    switch (blockIdx.z) {
        case 0: d = pack.g[0]; break;
        case 1: d = pack.g[1]; break;
        case 2: d = pack.g[2]; break;
        case 3: d = pack.g[3]; break;
        case 4: d = pack.g[4]; break;
        default: d = pack.g[5]; break;
    }
    const int n0 = blockIdx.y * 64;
    if (n0 >= d.N) return;
    const int k0 = blockIdx.x * 64;

    __shared__ float T[64][68];
    const int t = threadIdx.x;

    {
        const int kr = t >> 2;
        const int c0 = (t & 3) << 4;
        const float* src = d.W + (size_t)(k0 + kr) * d.N + n0 + c0;
        f32x4 v0 = *(const f32x4*)(src);
        f32x4 v1 = *(const f32x4*)(src + 4);
        f32x4 v2 = *(const f32x4*)(src + 8);
        f32x4 v3 = *(const f32x4*)(src + 12);
#pragma unroll
        for (int i = 0; i < 4; ++i) T[c0 + i][kr]      = v0[i];
#pragma unroll
        for (int i = 0; i < 4; ++i) T[c0 + 4 + i][kr]  = v1[i];
#pragma unroll
        for (int i = 0; i < 4; ++i) T[c0 + 8 + i][kr]  = v2[i];
#pragma unroll
        for (int i = 0; i < 4; ++i) T[c0 + 12 + i][kr] = v3[i];
    }
    __syncthreads();

    {
        const int n  = t >> 2;
        const int kj = (t & 3) << 4;
        half8 h0, l0, h1, l1;
        f32x4 u0 = *(const f32x4*)&T[n][kj];
        f32x4 u1 = *(const f32x4*)&T[n][kj + 4];
        f32x4 u2 = *(const f32x4*)&T[n][kj + 8];
        f32x4 u3 = *(const f32x4*)&T[n][kj + 12];
        u0 *= WSCALE; u1 *= WSCALE; u2 *= WSCALE; u3 *= WSCALE;
        split8(u0, u1, &h0, &l0);
        split8(u2, u3, &h1, &l1);
        const size_t o = (size_t)(n0 + n) * d.K + k0 + kj;
        *(half8*)(d.oh + o)     = h0;
        *(half8*)(d.oh + o + 8) = h1;
        *(half8*)(d.ol + o)     = l0;
        *(half8*)(d.ol + o + 8) = l1;
    }
}

// ---------------------------------------------------------------------------
// N=16 weight split+transpose: W fp32 [K,16] -> [16,K] h/l, x64.
// ---------------------------------------------------------------------------
struct W16Desc { const float* W; _Float16* oh; _Float16* ol; int K; };
struct W16Pack { W16Desc g[5]; };

__global__ __launch_bounds__(256) void w16split_kernel(W16Pack pack)
{
    W16Desc d;
    switch (blockIdx.z) {
        case 0: d = pack.g[0]; break;
        case 1: d = pack.g[1]; break;
        case 2: d = pack.g[2]; break;
        case 3: d = pack.g[3]; break;
        default: d = pack.g[4]; break;
    }
    const int k = blockIdx.x * 256 + threadIdx.x;
    if (k >= d.K) return;
    const float* src = d.W + (size_t)k * E_;
#pragma unroll
    for (int n = 0; n < E_; ++n) {
        float v = src[n] * WSCALE;
        _Float16 h = (_Float16)v;
        d.oh[(size_t)n * d.K + k] = h;
        d.ol[(size_t)n * d.K + k] = (_Float16)(v - (float)h);
    }
}

// ---------------------------------------------------------------------------
// b23 = bm2 @ Ws1[2+m] + bs1[2+m]: split-K partials + reduce
// ---------------------------------------------------------------------------
__global__ __launch_bounds__(256) void b23_partial_kernel(
    const float* __restrict__ bm2, const float* __restrict__ Ws1,
    float* __restrict__ pb23)
{
    const int idx = blockIdx.x * 256 + threadIdx.x;   // 0..16383
    const int n = idx & 1023;
    const int m = (idx >> 10) & 1;
    const int c = idx >> 11;                          // 0..7
    const float* W = Ws1 + (size_t)(2 + m) * H_ * H2_ + n;
    float s = 0.f;
    const int k0 = c * 256;
    for (int k = k0; k < k0 + 256; ++k)
        s = fmaf(bm2[k], W[(size_t)k * H2_], s);
    pb23[((size_t)c << 11) + (m << 10) + n] = s;
}

__global__ __launch_bounds__(256) void b23_reduce_kernel(
    const float* __restrict__ pb23, const float* __restrict__ bs1,
    float* __restrict__ b23)
{
    const int idx = blockIdx.x * 256 + threadIdx.x;   // 0..2047
    float s = 0.f;
#pragma unroll
    for (int c = 0; c < 8; ++c) s += pb23[(c << 11) + idx];
    const int m = idx >> 10, n = idx & 1023;
    b23[idx] = s + bs1[(2 + m) * H2_ + n];
}

// ---------------------------------------------------------------------------
// f16x3 MFMA GEMM, 256x256 tile (R5/R6 schedule, K-loop unchanged):
//   512 threads = 8 waves (4M x 2N); per-wave 64x128 = acc[4][8].
//   A: A2 global->reg each K-step. B: [N,K] h/l via global_load_lds,
//   double-buffered 64 KB LDS; counted vmcnt(4).
// mode 0: fp32 out (+bias,+relu); mode 1: f16 h/l out in A2 layout (+bias,
//   +relu opt); mode 2: raw fp32 partial; mode 3: raw h/l TRANSPOSED [N,M]
//   (B-operand format for a later GEMM, no scale -- keeps the x64).
// ---------------------------------------------------------------------------
struct GDesc {
    const _Float16* Ah; const _Float16* Al;
    const _Float16* Wh; const _Float16* Wl;
    const float* bias; float* Cf; _Float16* Ch; _Float16* Cl;
    int K; int ldk; int k0; int N; int ntn; int relu; int mode;
};
struct GPack { GDesc g[8]; };

__global__ __launch_bounds__(512, 2) void gemm_mfma_kernel(GPack pack)
{
    GDesc d;
    switch (blockIdx.z) {
        case 0: d = pack.g[0]; break;
        case 1: d = pack.g[1]; break;
        case 2: d = pack.g[2]; break;
        case 3: d = pack.g[3]; break;
        case 4: d = pack.g[4]; break;
        case 5: d = pack.g[5]; break;
        case 6: d = pack.g[6]; break;
        default: d = pack.g[7]; break;
    }
    const int mt_ = blockIdx.x >> 2;
    const int nt_ = (blockIdx.y << 2) + (blockIdx.x & 3);
    if (nt_ >= d.ntn) return;
    const int bm = mt_ * 256, bn = nt_ * 256;
    const int K = d.K, N = d.N, ldk = d.ldk;

    // B granule layout (<=2-way bank aliasing, verified conflict-free)
    __shared__ _Float16 Bh_s[2][256 * 32];   // 16 KB x 2
    __shared__ _Float16 Bl_s[2][256 * 32];   // total 64 KB

    const int tid  = threadIdx.x;
    const int lane = tid & 63;
    const int wave = tid >> 6;               // 0..7
    const int wm = wave >> 1, wn = wave & 1; // 4M x 2N

    size_t b_goff[2];
    int    s_lo[2];
#pragma unroll
    for (int is = 0; is < 2; ++is) {
        const int g = tid + (is << 9);
        const int row = g >> 2;
        const int q = ((g & 3) - (row >> 1)) & 3;
        b_goff[is] = (size_t)(bn + row) * ldk + d.k0 + q * 8;
        s_lo[is]   = g * 8;
    }

    const int bn0  = wn * 128 + (lane & 15);
    const int boff = (bn0 * 4 + (((lane >> 4) + (bn0 >> 1)) & 3)) * 8;

    const int aoff0 = (bm + wm * 64 + (lane & 15)) * 32 + (lane >> 4) * 8;
    const int aplane0 = d.k0 >> 5;

    f32x4 acc[4][8];
#pragma unroll
    for (int i = 0; i < 4; ++i)
#pragma unroll
        for (int j = 0; j < 8; ++j) acc[i][j] = (f32x4)0.f;

    auto issue_tile = [&](int kk, int c) {
#pragma unroll
        for (int is = 0; is < 2; ++is) {
            load_lds16(d.Wh + b_goff[is] + kk, &Bh_s[c][s_lo[is]]);
            load_lds16(d.Wl + b_goff[is] + kk, &Bl_s[c][s_lo[is]]);
        }
    };

    issue_tile(0, 0);

    const int niter = K >> 5;
    for (int it = 0; it < niter; ++it) {
        const int cur = it & 1;

        half8 fAh[4], fAl[4];
        {
            const size_t pl = ((size_t)(aplane0 + it)) << 16;
            const _Float16* pah = d.Ah + pl + aoff0;
            const _Float16* pal = d.Al + pl + aoff0;
#pragma unroll
            for (int mt = 0; mt < 4; ++mt) {
                fAh[mt] = *(const half8*)(pah + mt * 512);
                fAl[mt] = *(const half8*)(pal + mt * 512);
            }
        }

        asm volatile("" ::: "memory");
        __builtin_amdgcn_s_barrier();

        if (it + 1 < niter) {
            issue_tile((it + 1) << 5, cur ^ 1);
            asm volatile("s_waitcnt vmcnt(4)" ::: "memory");
        } else {
            asm volatile("s_waitcnt vmcnt(0)" ::: "memory");
        }

        __builtin_amdgcn_s_barrier();
        asm volatile("" ::: "memory");

        __builtin_amdgcn_s_setprio(1);
#pragma unroll
        for (int nt = 0; nt < 8; ++nt) {
            half8 fBh = *(const half8*)&Bh_s[cur][boff + nt * 512];
            half8 fBl = *(const half8*)&Bl_s[cur][boff + nt * 512];
#pragma unroll
            for (int mt = 0; mt < 4; ++mt) {
                acc[mt][nt] = __builtin_amdgcn_mfma_f32_16x16x32_f16(
                    fAh[mt], fBh, acc[mt][nt], 0, 0, 0);
                acc[mt][nt] = __builtin_amdgcn_mfma_f32_16x16x32_f16(
                    fAh[mt], fBl, acc[mt][nt], 0, 0, 0);
                acc[mt][nt] = __builtin_amdgcn_mfma_f32_16x16x32_f16(
                    fAl[mt], fBh, acc[mt][nt], 0, 0, 0);
            }
        }
        __builtin_amdgcn_s_setprio(0);
    }

    // epilogue: C/D layout col=lane&15, row=(lane>>4)*4+reg
    const int erow0 = bm + wm * 64 + ((lane >> 4) << 2);
    const int ecol0 = bn + wn * 128 + (lane & 15);

    if (d.mode == 3) {
        // transposed raw h/l: out[col][row], ld = M_TOK (2048)
#pragma unroll
        for (int nt = 0; nt < 8; ++nt) {
            const int col = ecol0 + nt * 16;
#pragma unroll
            for (int mt = 0; mt < 4; ++mt) {
                f32x4 a = acc[mt][nt];
                half4 hv, lv;
#pragma unroll
                for (int r = 0; r < 4; ++r) {
                    _Float16 h = (_Float16)a[r];
                    hv[r] = h;
                    lv[r] = (_Float16)(a[r] - (float)h);
                }
                const size_t o = (size_t)col * M_TOK + erow0 + mt * 16;
                *(half4*)(d.Ch + o) = hv;
                *(half4*)(d.Cl + o) = lv;
            }
        }
        return;
    }

#pragma unroll
    for (int nt = 0; nt < 8; ++nt) {
        const int col = ecol0 + nt * 16;
        const float bb = (d.mode == 2) ? 0.f : d.bias[col];
        const size_t colbase = ((size_t)(col >> 5) << 16) + (size_t)(col & 31);
#pragma unroll
        for (int mt = 0; mt < 4; ++mt) {
            f32x4 a = acc[mt][nt];
#pragma unroll
            for (int r = 0; r < 4; ++r) {
                const int rr = erow0 + mt * 16 + r;
                if (d.mode == 2) {
                    d.Cf[(size_t)rr * N + col] = a[r];      // raw partial
                } else {
                    float v = a[r] * INV_WSCALE + bb;
                    if (d.relu) v = fmaxf(v, 0.f);
                    if (d.mode == 0) {
                        d.Cf[(size_t)rr * N + col] = v;
                    } else {
                        const size_t o2 = colbase + (size_t)rr * 32;
                        _Float16 h = (_Float16)v;
                        d.Ch[o2] = h;
                        d.Cl[o2] = (_Float16)(v - (float)h);
                    }
                }
            }
        }
    }
}

// ---------------------------------------------------------------------------
// 4-way split-K combine: v = (P0+P1+P2+P3)*(1/64) + bias, relu,
// output f16 h/l in A2 layout (N=1024).
// ---------------------------------------------------------------------------
struct C4Desc {
    const float* P0; const float* P1; const float* P2; const float* P3;
    const float* bias; _Float16* Ch; _Float16* Cl; int N;
};
struct C4Pack { C4Desc g[2]; };

__global__ __launch_bounds__(256) void combine4_kernel(C4Pack pack)
{
    C4Desc d;
    switch (blockIdx.z) {
        case 0: d = pack.g[0]; break;
        default: d = pack.g[1]; break;
    }
    const size_t i = ((size_t)blockIdx.x * 256 + threadIdx.x) * 8;
    f32x4 s0 = *(const f32x4*)(d.P0 + i)     + *(const f32x4*)(d.P1 + i);
    f32x4 s1 = *(const f32x4*)(d.P0 + i + 4) + *(const f32x4*)(d.P1 + i + 4);
    s0 += *(const f32x4*)(d.P2 + i)     + *(const f32x4*)(d.P3 + i);
    s1 += *(const f32x4*)(d.P2 + i + 4) + *(const f32x4*)(d.P3 + i + 4);
    const int c0 = (int)(i & (size_t)(d.N - 1));
    f32x4 bb0 = *(const f32x4*)(d.bias + c0);
    f32x4 bb1 = *(const f32x4*)(d.bias + c0 + 4);
    f32x4 v0 = s0 * INV_WSCALE + bb0;
    f32x4 v1 = s1 * INV_WSCALE + bb1;
#pragma unroll
    for (int j = 0; j < 4; ++j) {
        v0[j] = fmaxf(v0[j], 0.f);
        v1[j] = fmaxf(v1[j], 0.f);
    }
    half8 h, l;
    split8(v0, v1, &h, &l);
    const size_t row = i >> 10;                     // N = 1024
    const size_t o2  = (((size_t)c0 >> 5) << 16) + row * 32 + (c0 & 31);
    *(half8*)(d.Ch + o2) = h;
    *(half8*)(d.Cl + o2) = l;
}

// ---------------------------------------------------------------------------
// Logit GEMM via MFMA: C[M,16] = A(h/l A2) @ Wt(h/l [16,K]) * 1/64 + bias.
// 256 threads = 4 waves, each wave 64 rows (acc[4]); no LDS, no barriers.
// ---------------------------------------------------------------------------
struct LDesc {
    const _Float16* Ah; const _Float16* Al;
    const _Float16* Wh; const _Float16* Wl;
    const float* bias; float* C; int K;
};
struct LPack { LDesc g[5]; };

__global__ __launch_bounds__(256) void logit_kernel(LPack pack)
{
    LDesc d;
    switch (blockIdx.z) {
        case 0: d = pack.g[0]; break;
        case 1: d = pack.g[1]; break;
        case 2: d = pack.g[2]; break;
        case 3: d = pack.g[3]; break;
        default: d = pack.g[4]; break;
    }
    const int tid  = threadIdx.x;
    const int lane = tid & 63;
    const int wave = tid >> 6;
    const int bm = blockIdx.x * 256 + wave * 64;
    const int K = d.K;

    const int aoff0 = (bm + (lane & 15)) * 32 + (lane >> 4) * 8;
    const int boff0 = (lane & 15) * K + (lane >> 4) * 8;

    f32x4 acc[4];
#pragma unroll
    for (int i = 0; i < 4; ++i) acc[i] = (f32x4)0.f;

    const int niter = K >> 5;
#pragma unroll 2
    for (int it = 0; it < niter; ++it) {
        const size_t pl = ((size_t)it << 16) + aoff0;   // plane stride 65536
        half8 bh = *(const half8*)(d.Wh + boff0 + it * 32);
        half8 bl = *(const half8*)(d.Wl + boff0 + it * 32);
#pragma unroll
        for (int mt = 0; mt < 4; ++mt) {
            half8 ah = *(const half8*)(d.Ah + pl + mt * 512);
            half8 al = *(const half8*)(d.Al + pl + mt * 512);
            acc[mt] = __builtin_amdgcn_mfma_f32_16x16x32_f16(ah, bh, acc[mt], 0, 0, 0);
            acc[mt] = __builtin_amdgcn_mfma_f32_16x16x32_f16(ah, bl, acc[mt], 0, 0, 0);
            acc[mt] = __builtin_amdgcn_mfma_f32_16x16x32_f16(al, bh, acc[mt], 0, 0, 0);
        }
    }

    const int erow0 = bm + ((lane >> 4) << 2);
    const int col = lane & 15;
    const float bb = d.bias[col];
#pragma unroll
    for (int mt = 0; mt < 4; ++mt)
#pragma unroll
        for (int r = 0; r < 4; ++r)
            d.C[(size_t)(erow0 + mt * 16 + r) * E_ + col] =
                acc[mt][r] * INV_WSCALE + bb;
}

// ---------------------------------------------------------------------------
// Router finalize
// ---------------------------------------------------------------------------
__device__ __forceinline__ void softmax16_acc(const float* __restrict__ lg,
                                              float w, float* __restrict__ p)
{
    float mx = lg[0];
#pragma unroll
    for (int e = 1; e < 16; ++e) mx = fmaxf(mx, lg[e]);
    float ex[16];
    float s = 0.f;
#pragma unroll
    for (int e = 0; e < 16; ++e) { ex[e] = expf(lg[e] - mx); s += ex[e]; }
    const float wi = w / s;
#pragma unroll
    for (int e = 0; e < 16; ++e) p[e] = fmaf(ex[e], wi, p[e]);
}

__global__ __launch_bounds__(256) void router_kernel(
    const float* __restrict__ GL, const float* __restrict__ SL,
    float* __restrict__ out, float* __restrict__ accum)
{
    const int t = blockIdx.x * 256 + threadIdx.x;

    float p[16];
#pragma unroll
    for (int e = 0; e < 16; ++e) p[e] = 0.f;

    softmax16_acc(GL + (size_t)t * E_, ALPHA_, p);
#pragma unroll
    for (int m = 0; m < 4; ++m)
        softmax16_acc(SL + ((size_t)m * M_TOK + t) * E_, (1.f - ALPHA_) * 0.5f, p);

    const size_t NTOT = (size_t)M_TOK * E_ * CAP_;
    float* probs_out = out + 2 * NTOT + (size_t)t * E_;
#pragma unroll
    for (int e = 0; e < 16; ++e) probs_out[e] = p[e];

    float red[16];
#pragma unroll
    for (int e = 0; e < 16; ++e) red[e] = p[e];
#pragma unroll
    for (int m = 1; m < 64; m <<= 1)
#pragma unroll
        for (int e = 0; e < 16; ++e) red[e] += __shfl_xor(red[e], m);
    const int lane = threadIdx.x & 63;
#pragma unroll
    for (int e = 0; e < 16; ++e)
        if (lane == e) atomicAdd(&accum[e], red[e]);

    float tmp[16];
#pragma unroll
    for (int e = 0; e < 16; ++e) tmp[e] = p[e];
    int   bi[4];
    float bv[4];
    float s4 = 0.f;
#pragma unroll
    for (int kk = 0; kk < 4; ++kk) {
        float best = -1.f; int besti = 0;
#pragma unroll
        for (int e = 0; e < 16; ++e)
            if (tmp[e] > best) { best = tmp[e]; besti = e; }
        bi[kk] = besti; bv[kk] = best; s4 += best;
        tmp[besti] = -1.f;
    }
    const float inv = 1.f / s4;
#pragma unroll
    for (int kk = 0; kk < 4; ++kk) {
        const size_t base = ((size_t)t * E_ + bi[kk]) * CAP_;
        out[base] = 1.0f;
        out[NTOT + base] = bv[kk] * inv;
    }
}

__global__ void aux_kernel(const float* __restrict__ accum,
                           float* __restrict__ out, unsigned long long pos)
{
    if (threadIdx.x == 0 && blockIdx.x == 0) {
        float s = 0.f;
#pragma unroll
        for (int e = 0; e < 16; ++e) {
            float m = accum[e] * (1.0f / (float)M_TOK);
            s += m * logf(m * (float)E_ + 1e-9f);
        }
        out[pos] = s;
    }
}

// ---------------------------------------------------------------------------
extern "C" void kernel_launch(void* const* d_in, const int* in_sizes, int n_in,
                              void* d_out, int out_size, void* d_ws, size_t ws_size,
                              hipStream_t stream)
{
    const float* hidden = (const float*)d_in[0];
    const float* mimg   = (const float*)d_in[1];
    const float* mgen   = (const float*)d_in[2];
    const float* Wg1 = (const float*)d_in[3];
    const float* bg1 = (const float*)d_in[4];
    const float* Wg2 = (const float*)d_in[5];
    const float* bg2 = (const float*)d_in[6];
    const float* Wm1 = (const float*)d_in[7];
    const float* bm1 = (const float*)d_in[8];
    const float* Wm2 = (const float*)d_in[9];
    const float* bm2 = (const float*)d_in[10];
    const float* Ws1 = (const float*)d_in[11];  // [4,H,H2]
    const float* bs1 = (const float*)d_in[12];  // [4,H2]
    const float* Ws2 = (const float*)d_in[13];  // [4,H2,E]
    const float* bs2 = (const float*)d_in[14];  // [4,E]

    float* out = (float*)d_out;

    // workspace layout
    char* p = (char*)d_ws;
    float* accum = (float*)p;            p += 256;
    float* b23   = (float*)p;            p += 8192;               // [2][1024]
    float* pb23  = (float*)p;            p += 65536;              // [8][2048]
    float* GL    = (float*)p;            p += (size_t)M_TOK * E_ * 4;
    float* SL    = (float*)p;            p += (size_t)4 * M_TOK * E_ * 4;
    _Float16* hid_h = (_Float16*)p;      p += (size_t)M_TOK * H_ * 2;
    _Float16* hid_l = (_Float16*)p;      p += (size_t)M_TOK * H_ * 2;
    _Float16* img_h = (_Float16*)p;      p += (size_t)M_TOK * H_ * 2;
    _Float16* img_l = (_Float16*)p;      p += (size_t)M_TOK * H_ * 2;
    _Float16* gen_h = (_Float16*)p;      p += (size_t)M_TOK * H_ * 2;
    _Float16* gen_l = (_Float16*)p;      p += (size_t)M_TOK * H_ * 2;
    _Float16* wm2a_h = (_Float16*)p;     p += (size_t)H_ * H_ * 2;
    _Float16* wm2a_l = (_Float16*)p;     p += (size_t)H_ * H_ * 2;
    _Float16* T1_h  = (_Float16*)p;      p += (size_t)M_TOK * H_ * 2;
    _Float16* T1_l  = (_Float16*)p;      p += (size_t)M_TOK * H_ * 2;
    _Float16* G1_h  = (_Float16*)p;      p += (size_t)M_TOK * H_ * 2;
    _Float16* G1_l  = (_Float16*)p;      p += (size_t)M_TOK * H_ * 2;
    _Float16* S1_h  = (_Float16*)p;      p += (size_t)4 * M_TOK * H2_ * 2;
    _Float16* S1_l  = (_Float16*)p;      p += (size_t)4 * M_TOK * H2_ * 2;
    _Float16* W23t_h = (_Float16*)p;     p += (size_t)2 * H2_ * H_ * 2;
    _Float16* W23t_l = (_Float16*)p;     p += (size_t)2 * H2_ * H_ * 2;
    _Float16* Wm1t_h = (_Float16*)p;     p += (size_t)H_ * H_ * 2;
    _Float16* Wm1t_l = (_Float16*)p;     p += (size_t)H_ * H_ * 2;
    _Float16* Wg1t_h = (_Float16*)p;     p += (size_t)H_ * H_ * 2;
    _Float16* Wg1t_l = (_Float16*)p;     p += (size_t)H_ * H_ * 2;
    _Float16* Ws1t_h = (_Float16*)p;     p += (size_t)4 * H2_ * H_ * 2;
    _Float16* Ws1t_l = (_Float16*)p;     p += (size_t)4 * H2_ * H_ * 2;
    _Float16* Ws2t_h = (_Float16*)p;     p += (size_t)(E_ * H_ + 4 * E_ * H2_) * 2;
    _Float16* Ws2t_l = (_Float16*)p;     p += (size_t)(E_ * H_ + 4 * E_ * H2_) * 2;

    // pc split-K=4 partials: 8 x [2048,1024] fp32 alias dead-after-pa regions
    float* PC[8] = { (float*)hid_h, (float*)hid_l, (float*)img_h, (float*)img_l,
                     (float*)gen_h, (float*)gen_l, (float*)wm2a_h, (float*)wm2a_l };

    hipMemsetAsync(d_out, 0, (size_t)out_size * sizeof(float), stream);
    hipMemsetAsync(accum, 0, 16 * sizeof(float), stream);

    const dim3 blk(256);
    const dim3 blkg(512);

    // 1) activation split (hidden, image, genomic, Wm2) -> A2 layout
    APack ap;
    ap.g[0] = {hidden, hid_h, hid_l};
    ap.g[1] = {mimg,   img_h, img_l};
    ap.g[2] = {mgen,   gen_h, gen_l};
    ap.g[3] = {Wm2,    wm2a_h, wm2a_l};
    asplit_kernel<<<dim3((M_TOK * H_) / (256 * 8), 1, 4), blk, 0, stream>>>(ap);

    // 2) weight split+transpose (x64): Wm1, Wg1, Ws1[0..3]
    WPack wp;
    wp.g[0] = {Wm1, Wm1t_h, Wm1t_l, H_, H_};
    wp.g[1] = {Wg1, Wg1t_h, Wg1t_l, H_, H_};
    for (int m = 0; m < 4; ++m)
        wp.g[2 + m] = {Ws1 + (size_t)m * H_ * H2_,
                       Ws1t_h + (size_t)m * H2_ * H_,
                       Ws1t_l + (size_t)m * H2_ * H_, H_, H2_};
    wsplit_kernel<<<dim3(32, 32, 6), blk, 0, stream>>>(wp);

    // 2b) N=16 weight splits: Wg2 [2048,16], Ws2[m] [1024,16]
    W16Pack w16;
    w16.g[0] = {Wg2, Ws2t_h, Ws2t_l, H_};
    for (int m = 0; m < 4; ++m)
        w16.g[1 + m] = {Ws2 + (size_t)m * H2_ * E_,
                        Ws2t_h + (size_t)E_ * H_ + (size_t)m * E_ * H2_,
                        Ws2t_l + (size_t)E_ * H_ + (size_t)m * E_ * H2_, H2_};
    w16split_kernel<<<dim3(8, 1, 5), blk, 0, stream>>>(w16);

    // 2c) fused bias b23 = bm2@Ws1[2+m] + bs1[2+m] (split-K + reduce)
    b23_partial_kernel<<<64, blk, 0, stream>>>(bm2, Ws1, pb23);
    b23_reduce_kernel<<<8, blk, 0, stream>>>(pb23, bs1, b23);

    // 3) L1 GEMMs + W23 weight GEMMs = 256 active blocks (1/CU exact)
    GPack pa;
    pa.g[0] = {hid_h, hid_l, Wm1t_h, Wm1t_l, bm1, nullptr, T1_h, T1_l,
               H_, H_, 0, H_, 8, 1, 1};
    pa.g[1] = {hid_h, hid_l, Wg1t_h, Wg1t_l, bg1, nullptr, G1_h, G1_l,
               H_, H_, 0, H_, 8, 1, 1};
    pa.g[2] = {img_h, img_l, Ws1t_h + (size_t)0 * H2_ * H_, Ws1t_l + (size_t)0 * H2_ * H_,
               bs1 + 0 * H2_, nullptr, S1_h + (size_t)0 * M_TOK * H2_,
               S1_l + (size_t)0 * M_TOK * H2_, H_, H_, 0, H2_, 4, 1, 1};
    pa.g[3] = {gen_h, gen_l, Ws1t_h + (size_t)1 * H2_ * H_, Ws1t_l + (size_t)1 * H2_ * H_,
               bs1 + 1 * H2_, nullptr, S1_h + (size_t)1 * M_TOK * H2_,
               S1_l + (size_t)1 * M_TOK * H2_, H_, H_, 0, H2_, 4, 1, 1};
    pa.g[4] = {wm2a_h, wm2a_l, Ws1t_h + (size_t)2 * H2_ * H_, Ws1t_l + (size_t)2 * H2_ * H_,
               nullptr, nullptr, W23t_h + (size_t)0 * H2_ * H_,
               W23t_l + (size_t)0 * H2_ * H_, H_, H_, 0, H2_, 4, 0, 3};
    pa.g[5] = {wm2a_h, wm2a_l, Ws1t_h + (size_t)3 * H2_ * H_, Ws1t_l + (size_t)3 * H2_ * H_,
               nullptr, nullptr, W23t_h + (size_t)1 * H2_ * H_,
               W23t_l + (size_t)1 * H2_ * H_, H_, H_, 0, H2_, 4, 0, 3};
    pa.g[6] = pa.g[0]; pa.g[7] = pa.g[0];
    gemm_mfma_kernel<<<dim3(32, 2, 6), blkg, 0, stream>>>(pa);

    // 4) pc: T1 @ W23t, split-K=4 -> 256 blocks (1/CU exact), raw partials
    GPack pc;
    for (int m = 0; m < 2; ++m)
        for (int c = 0; c < 4; ++c)
            pc.g[m * 4 + c] = {T1_h, T1_l,
                W23t_h + (size_t)m * H2_ * H_, W23t_l + (size_t)m * H2_ * H_,
                nullptr, PC[m * 4 + c], nullptr, nullptr,
                H_ / 4, H_, c * (H_ / 4), H2_, 4, 0, 2};
    gemm_mfma_kernel<<<dim3(32, 1, 8), blkg, 0, stream>>>(pc);

    // 4b) combine 4-way -> S1[2], S1[3] h/l A2 (+b23 bias +relu)
    C4Pack cc;
    cc.g[0] = {PC[0], PC[1], PC[2], PC[3], b23,
               S1_h + (size_t)2 * M_TOK * H2_, S1_l + (size_t)2 * M_TOK * H2_, H2_};
    cc.g[1] = {PC[4], PC[5], PC[6], PC[7], b23 + 1024,
               S1_h + (size_t)3 * M_TOK * H2_, S1_l + (size_t)3 * M_TOK * H2_, H2_};
    combine4_kernel<<<dim3((M_TOK * H2_) / (256 * 8), 1, 2), blk, 0, stream>>>(cc);

    // 5) logit GEMMs via MFMA
    LPack lp;
    lp.g[0] = {G1_h, G1_l, Ws2t_h, Ws2t_l, bg2, GL, H_};
    for (int m = 0; m < 4; ++m)
        lp.g[1 + m] = {S1_h + (size_t)m * M_TOK * H2_, S1_l + (size_t)m * M_TOK * H2_,
                       Ws2t_h + (size_t)E_ * H_ + (size_t)m * E_ * H2_,
                       Ws2t_l + (size_t)E_ * H_ + (size_t)m * E_ * H2_,
                       bs2 + (size_t)m * E_, SL + (size_t)m * M_TOK * E_, H2_};
    logit_kernel<<<dim3(8, 1, 5), blk, 0, stream>>>(lp);

    // 6) finalize
    router_kernel<<<M_TOK / 256, blk, 0, stream>>>(GL, SL, out, accum);
    aux_kernel<<<1, 64, 0, stream>>>(accum, out, (unsigned long long)out_size - 1);
}